// Round 7
// baseline (73.442 us; speedup 1.0000x reference)
//
#include <hip/hip_runtime.h>

#define NSPIN   64
#define BATCH_N 1000000
#define NTILES  (BATCH_N / 16)   // 62500 16-row tiles
#define NBLOCKS 3125
#define NWAVES  (NBLOCKS * 4)    // 12500 waves -> exactly 5 tiles/wave

typedef __bf16 bf16x8 __attribute__((ext_vector_type(8)));
typedef float  f32x4  __attribute__((ext_vector_type(4)));

__device__ __forceinline__ unsigned fbits(float x) {
    union { float f; unsigned u; } cv; cv.f = x; return cv.u;
}
// pack two fp32 into packed bf16x2 (truncation — exact for +/-1.0)
__device__ __forceinline__ unsigned pack2(float lo, float hi) {
    return __builtin_amdgcn_perm(fbits(hi), fbits(lo), 0x07060302u);
}

__global__ __launch_bounds__(256, 4) void ham_kernel(
    const float* __restrict__ states,
    const float* __restrict__ couplings,
    const float* __restrict__ fields,
    float* __restrict__ out)
{
    const int lane = threadIdx.x & 63;
    const int wid  = threadIdx.x >> 6;
    const int lo16 = lane & 15;   // J row (A) / batch col (D)
    const int g4   = lane >> 4;   // k-group; D rows 4*g4+q
    const int gw   = blockIdx.x * 4 + wid;

    // Build symmetric bf16 J (zero diag) in LDS, once per block (overlapped
    // across blocks — no serial prologue kernel in the graph).
    __shared__ __bf16 J[NSPIN * NSPIN];
    for (int i = threadIdx.x; i < NSPIN * NSPIN; i += 256) {
        int r = i >> 6, c = i & 63;
        float v = 0.0f;
        if (r > c)      v = couplings[(r * (r - 1)) / 2 + c];
        else if (r < c) v = couplings[(c * (c - 1)) / 2 + r];
        J[i] = (__bf16)v;
    }
    __syncthreads();

    // A fragments (J rows): jf[nb][kb] = J[16nb+lo16][32kb+8g4+e]
    bf16x8 jf[4][2];
#pragma unroll
    for (int nb = 0; nb < 4; ++nb)
#pragma unroll
        for (int kb = 0; kb < 2; ++kb)
            jf[nb][kb] = *(const bf16x8*)(J + (nb * 16 + lo16) * NSPIN + kb * 32 + g4 * 8);

    // acc init = fields along m: ffrag[nb][q] = f[16nb+4g4+q]
    f32x4 ffrag[4];
#pragma unroll
    for (int nb = 0; nb < 4; ++nb)
        ffrag[nb] = *(const f32x4*)(fields + nb * 16 + g4 * 4);

    // ---- pure-register streaming loop: no LDS staging, TLP hides HBM ----
    for (int t = gw; t < NTILES; t += NWAVES) {
        const float* row = states + (size_t)t * (16 * NSPIN) + lo16 * NSPIN;

        // S^T B-fragment: S[lo16][32kb+8g4+e] — 4x dwordx4, wave covers tile
        f32x4 a0 = *(const f32x4*)(row + g4 * 8);
        f32x4 a1 = *(const f32x4*)(row + g4 * 8 + 4);
        f32x4 a2 = *(const f32x4*)(row + 32 + g4 * 8);
        f32x4 a3 = *(const f32x4*)(row + 32 + g4 * 8 + 4);

        // rv[nb] = S[lo16][16nb+4g4 .. +3] — same 256B row, L1 hits
        f32x4 rv[4];
#pragma unroll
        for (int nb = 0; nb < 4; ++nb)
            rv[nb] = *(const f32x4*)(row + nb * 16 + g4 * 4);

        union { bf16x8 v; unsigned u[4]; } af0, af1;
        af0.u[0] = pack2(a0[0], a0[1]);
        af0.u[1] = pack2(a0[2], a0[3]);
        af0.u[2] = pack2(a1[0], a1[1]);
        af0.u[3] = pack2(a1[2], a1[3]);
        af1.u[0] = pack2(a2[0], a2[1]);
        af1.u[1] = pack2(a2[2], a2[3]);
        af1.u[2] = pack2(a3[0], a3[1]);
        af1.u[3] = pack2(a3[2], a3[3]);

        // D = J*S^T + F : row m=16nb+4g4+q (spin), col n=lo16 (batch)
        f32x4 acc[4];
#pragma unroll
        for (int nb = 0; nb < 4; ++nb) acc[nb] = ffrag[nb];
#pragma unroll
        for (int nb = 0; nb < 4; ++nb) {
            acc[nb] = __builtin_amdgcn_mfma_f32_16x16x32_bf16(jf[nb][0], af0.v, acc[nb], 0, 0, 0);
            acc[nb] = __builtin_amdgcn_mfma_f32_16x16x32_bf16(jf[nb][1], af1.v, acc[nb], 0, 0, 0);
        }

        // H[b=lo16] = -sum_m s_b[m]*acc[m][b]; lane-local dot, 2-step reduce
        float p = 0.f;
#pragma unroll
        for (int nb = 0; nb < 4; ++nb) {
            p += rv[nb][0] * acc[nb][0];
            p += rv[nb][1] * acc[nb][1];
            p += rv[nb][2] * acc[nb][2];
            p += rv[nb][3] * acc[nb][3];
        }
        p += __shfl_xor(p, 16, 64);
        p += __shfl_xor(p, 32, 64);
        if (g4 == 0)
            out[t * 16 + lo16] = -p;   // lanes 0-15, coalesced 64B
    }
}

extern "C" void kernel_launch(void* const* d_in, const int* in_sizes, int n_in,
                              void* d_out, int out_size, void* d_ws, size_t ws_size,
                              hipStream_t stream) {
    const float* states    = (const float*)d_in[0];
    const float* couplings = (const float*)d_in[1];
    const float* fields    = (const float*)d_in[2];
    float* out = (float*)d_out;
    ham_kernel<<<NBLOCKS, 256, 0, stream>>>(states, couplings, fields, out);
}

// Round 8
// 52.401 us; speedup vs baseline: 1.4015x; 1.4015x over previous
//
#include <hip/hip_runtime.h>

#define NSPIN   64
#define BATCH_N 1000000
#define NTILES  (BATCH_N / 16)    // 62500 16-row tiles
#define NBLOCKS 3125
#define NWAVES  (NBLOCKS * 4)     // 12500 waves
#define TPW     (NTILES / NWAVES) // exactly 5 tiles/wave

typedef __bf16 bf16x8 __attribute__((ext_vector_type(8)));
typedef float  f32x4  __attribute__((ext_vector_type(4)));

__device__ __forceinline__ unsigned fbits(float x) {
    union { float f; unsigned u; } cv; cv.f = x; return cv.u;
}
// pack two fp32 into packed bf16x2 (truncation — exact for +/-1.0)
__device__ __forceinline__ unsigned pack2(float lo, float hi) {
    return __builtin_amdgcn_perm(fbits(hi), fbits(lo), 0x07060302u);
}

// async global->LDS, 16B per lane; LDS dest = uniform base + lane*16
__device__ __forceinline__ void gload_lds16(const void* g, void* l) {
    __builtin_amdgcn_global_load_lds(
        (const __attribute__((address_space(1))) unsigned int*)g,
        (__attribute__((address_space(3))) unsigned int*)l, 16, 0, 0);
}

__global__ __launch_bounds__(256, 4) void ham_kernel(
    const float* __restrict__ states,
    const float* __restrict__ couplings,
    const float* __restrict__ fields,
    float* __restrict__ out)
{
    // 4 waves x 3 x 4KB wave-private staging buffers (wave w at w*12K).
    // First 8KB temporarily holds J during the block prologue.
    __shared__ char smem[48 * 1024];

    const int lane = threadIdx.x & 63;
    const int wid  = threadIdx.x >> 6;
    const int lo16 = lane & 15;   // J row (A) / batch col (D)
    const int g4   = lane >> 4;   // k-group; D rows 4*g4+q
    const int gw   = blockIdx.x * 4 + wid;

    // Build symmetric bf16 J (zero diag) in LDS, hoist fragments, then the
    // region is recycled as wave0's staging buffers (no prologue kernel).
    bf16x8 jf[4][2];   // jf[nb][kb] = J[16nb+lo16][32kb+8g4+e]
    {
        __bf16* J = (__bf16*)smem;
        for (int i = threadIdx.x; i < NSPIN * NSPIN; i += 256) {
            int r = i >> 6, c = i & 63;
            float v = 0.0f;
            if (r > c)      v = couplings[(r * (r - 1)) / 2 + c];
            else if (r < c) v = couplings[(c * (c - 1)) / 2 + r];
            J[i] = (__bf16)v;
        }
        __syncthreads();
#pragma unroll
        for (int nb = 0; nb < 4; ++nb)
#pragma unroll
            for (int kb = 0; kb < 2; ++kb)
                jf[nb][kb] = *(const bf16x8*)(J + (nb * 16 + lo16) * NSPIN + kb * 32 + g4 * 8);
        __syncthreads();   // J region becomes wave0's staging buffers
    }

    // acc init = fields along m: ffrag[nb][q] = f[16nb+4g4+q]
    f32x4 ffrag[4];
#pragma unroll
    for (int nb = 0; nb < 4; ++nb)
        ffrag[nb] = *(const f32x4*)(fields + nb * 16 + g4 * 4);

    char* mybuf = smem + wid * (3 * 4096);   // three 4KB buffers, wave-private

    // Per-lane swizzled global source offsets for the 4 staging instrs.
    // LDS[row][chunk] = G[row][chunk ^ (row&7)]  (16B chunks, XOR involution)
    int srcoff[4];
#pragma unroll
    for (int j = 0; j < 4; ++j) {
        int row   = 4 * j + g4;
        int chunk = lo16 ^ (row & 7);
        srcoff[j] = row * 256 + chunk * 16;
    }

    const char* sbase = (const char*)states;
    auto stage = [&](int buf, int t) {
        const char* src = sbase + (size_t)t * 4096;
#pragma unroll
        for (int j = 0; j < 4; ++j)
            gload_lds16(src + srcoff[j], mybuf + buf * 4096 + j * 1024);
    };

    // Loop-invariant swizzled LDS read offsets (all reads use row = lo16):
    // addr(row, c) = row*256 + (c ^ ((row&7)<<4))
    const int sw  = (lo16 & 7) << 4;
    const int rb  = lo16 * 256;
    int aoff[4], roff[4];
    aoff[0] = rb + ((g4 * 32)            ^ sw);
    aoff[1] = rb + ((g4 * 32 + 16)       ^ sw);
    aoff[2] = rb + ((128 + g4 * 32)      ^ sw);
    aoff[3] = rb + ((128 + g4 * 32 + 16) ^ sw);
#pragma unroll
    for (int nb = 0; nb < 4; ++nb)
        roff[nb] = rb + ((nb * 64 + g4 * 16) ^ sw);

    // ---- 3-deep pipeline: loads issued 2 compute-phases ahead ----
    stage(0, gw);
    stage(1, gw + NWAVES);

#pragma unroll
    for (int i = 0; i < TPW; ++i) {
        const int t = gw + i * NWAVES;
        if (i + 2 < TPW) {
            stage((i + 2) % 3, t + 2 * NWAVES);
            asm volatile("s_waitcnt vmcnt(8)" ::: "memory");   // tile i staged
        } else if (i + 2 == TPW) {
            asm volatile("s_waitcnt vmcnt(4)" ::: "memory");
        } else {
            asm volatile("s_waitcnt vmcnt(0)" ::: "memory");
        }
        __builtin_amdgcn_sched_barrier(0);

        const char* B = mybuf + (i % 3) * 4096;

        // B-operand fragments: S^T[k][n=lo16] = S[lo16][k], contiguous row
        f32x4 a0 = *(const f32x4*)(B + aoff[0]);
        f32x4 a1 = *(const f32x4*)(B + aoff[1]);
        f32x4 a2 = *(const f32x4*)(B + aoff[2]);
        f32x4 a3 = *(const f32x4*)(B + aoff[3]);

        // rv[nb] = S[lo16][16nb+4g4 .. +3] -> one b128 per nb
        f32x4 rv[4];
#pragma unroll
        for (int nb = 0; nb < 4; ++nb)
            rv[nb] = *(const f32x4*)(B + roff[nb]);

        union { bf16x8 v; unsigned u[4]; } af0, af1;
        af0.u[0] = pack2(a0[0], a0[1]);
        af0.u[1] = pack2(a0[2], a0[3]);
        af0.u[2] = pack2(a1[0], a1[1]);
        af0.u[3] = pack2(a1[2], a1[3]);
        af1.u[0] = pack2(a2[0], a2[1]);
        af1.u[1] = pack2(a2[2], a2[3]);
        af1.u[2] = pack2(a3[0], a3[1]);
        af1.u[3] = pack2(a3[2], a3[3]);

        // D = J*S^T + F : row m=16nb+4g4+q (spin), col n=lo16 (batch)
        f32x4 acc[4];
#pragma unroll
        for (int nb = 0; nb < 4; ++nb) acc[nb] = ffrag[nb];
#pragma unroll
        for (int nb = 0; nb < 4; ++nb) {
            acc[nb] = __builtin_amdgcn_mfma_f32_16x16x32_bf16(jf[nb][0], af0.v, acc[nb], 0, 0, 0);
            acc[nb] = __builtin_amdgcn_mfma_f32_16x16x32_bf16(jf[nb][1], af1.v, acc[nb], 0, 0, 0);
        }

        // H[b=lo16] = -sum_m s_b[m]*acc[m][b]; lane-local dot, 2-step reduce
        float p = 0.f;
#pragma unroll
        for (int nb = 0; nb < 4; ++nb) {
            p += rv[nb][0] * acc[nb][0];
            p += rv[nb][1] * acc[nb][1];
            p += rv[nb][2] * acc[nb][2];
            p += rv[nb][3] * acc[nb][3];
        }
        p += __shfl_xor(p, 16, 64);
        p += __shfl_xor(p, 32, 64);
        if (g4 == 0)
            out[t * 16 + lo16] = -p;   // lanes 0-15, coalesced 64B
    }
}

extern "C" void kernel_launch(void* const* d_in, const int* in_sizes, int n_in,
                              void* d_out, int out_size, void* d_ws, size_t ws_size,
                              hipStream_t stream) {
    const float* states    = (const float*)d_in[0];
    const float* couplings = (const float*)d_in[1];
    const float* fields    = (const float*)d_in[2];
    float* out = (float*)d_out;
    ham_kernel<<<NBLOCKS, 256, 0, stream>>>(states, couplings, fields, out);
}

// Round 9
// 51.564 us; speedup vs baseline: 1.4243x; 1.0162x over previous
//
#include <hip/hip_runtime.h>

#define NSPIN   64
#define BATCH_N 1000000
#define NTILES  (BATCH_N / 16)    // 62500 16-row tiles
#define NBLOCKS 3125
#define NWAVES  (NBLOCKS * 4)     // 12500 waves
#define TPW     (NTILES / NWAVES) // exactly 5 tiles/wave

typedef __bf16 bf16x8 __attribute__((ext_vector_type(8)));
typedef float  f32x4  __attribute__((ext_vector_type(4)));

// Build symmetric bf16 J (zero diag) from lower-tri coupling vector, once.
__global__ void build_J_kernel(const float* __restrict__ couplings,
                               __bf16* __restrict__ Jg) {
    int idx = blockIdx.x * blockDim.x + threadIdx.x;
    if (idx >= NSPIN * NSPIN) return;
    int r = idx >> 6, c = idx & 63;
    float v = 0.0f;
    if (r > c)      v = couplings[(r * (r - 1)) / 2 + c];
    else if (r < c) v = couplings[(c * (c - 1)) / 2 + r];
    Jg[idx] = (__bf16)v;
}

__device__ __forceinline__ unsigned fbits(float x) {
    union { float f; unsigned u; } cv; cv.f = x; return cv.u;
}
// pack two fp32 into packed bf16x2 (truncation — exact for +/-1.0)
__device__ __forceinline__ unsigned pack2(float lo, float hi) {
    return __builtin_amdgcn_perm(fbits(hi), fbits(lo), 0x07060302u);
}

// async global->LDS, 16B per lane; NT (streaming) cache policy: the states
// stream has zero reuse — don't let it churn L2.
__device__ __forceinline__ void gload_lds16(const void* g, void* l) {
    __builtin_amdgcn_global_load_lds(
        (const __attribute__((address_space(1))) unsigned int*)g,
        (__attribute__((address_space(3))) unsigned int*)l, 16, 0, 2 /*NT*/);
}

template<bool USE_WS>
__global__ __launch_bounds__(256, 4) void ham_kernel(
    const float* __restrict__ states,
    const float* __restrict__ couplings,
    const float* __restrict__ fields,
    const __bf16* __restrict__ Jg,
    float* __restrict__ out)
{
    // 4 waves x 3 x 4KB wave-private staging buffers (wave w at w*12K).
    // (!USE_WS: first 8KB temporarily holds J during the prologue.)
    __shared__ char smem[48 * 1024];

    const int lane = threadIdx.x & 63;
    const int wid  = threadIdx.x >> 6;
    const int lo16 = lane & 15;   // J row (A) / batch col (D)
    const int g4   = lane >> 4;   // k-group; D rows 4*g4+q
    const int gw   = blockIdx.x * 4 + wid;

    // A fragments (J rows): jf[nb][kb] = J[16nb+lo16][32kb+8g4+e]
    bf16x8 jf[4][2];
    if constexpr (USE_WS) {
#pragma unroll
        for (int nb = 0; nb < 4; ++nb)
#pragma unroll
            for (int kb = 0; kb < 2; ++kb)
                jf[nb][kb] = *(const bf16x8*)(Jg + (nb * 16 + lo16) * NSPIN + kb * 32 + g4 * 8);
    } else {
        __bf16* J = (__bf16*)smem;
        for (int i = threadIdx.x; i < NSPIN * NSPIN; i += 256) {
            int r = i >> 6, c = i & 63;
            float v = 0.0f;
            if (r > c)      v = couplings[(r * (r - 1)) / 2 + c];
            else if (r < c) v = couplings[(c * (c - 1)) / 2 + r];
            J[i] = (__bf16)v;
        }
        __syncthreads();
#pragma unroll
        for (int nb = 0; nb < 4; ++nb)
#pragma unroll
            for (int kb = 0; kb < 2; ++kb)
                jf[nb][kb] = *(const bf16x8*)(J + (nb * 16 + lo16) * NSPIN + kb * 32 + g4 * 8);
        __syncthreads();   // J region becomes wave0's staging buffers
    }

    // acc init = fields along m: ffrag[nb][q] = f[16nb+4g4+q]
    f32x4 ffrag[4];
#pragma unroll
    for (int nb = 0; nb < 4; ++nb)
        ffrag[nb] = *(const f32x4*)(fields + nb * 16 + g4 * 4);

    char* mybuf = smem + wid * (3 * 4096);   // three 4KB buffers, wave-private

    // Per-lane swizzled global source offsets for the 4 staging instrs.
    // LDS[row][chunk] = G[row][chunk ^ (row&7)]  (16B chunks, XOR involution)
    int srcoff[4];
#pragma unroll
    for (int j = 0; j < 4; ++j) {
        int row   = 4 * j + g4;
        int chunk = lo16 ^ (row & 7);
        srcoff[j] = row * 256 + chunk * 16;
    }

    const char* sbase = (const char*)states;
    auto stage = [&](int buf, int t) {
        const char* src = sbase + (size_t)t * 4096;
#pragma unroll
        for (int j = 0; j < 4; ++j)
            gload_lds16(src + srcoff[j], mybuf + buf * 4096 + j * 1024);
    };

    // Loop-invariant swizzled LDS read offsets (all reads use row = lo16):
    // addr(row, c) = row*256 + (c ^ ((row&7)<<4))
    const int sw  = (lo16 & 7) << 4;
    const int rb  = lo16 * 256;
    int aoff[4], roff[4];
    aoff[0] = rb + ((g4 * 32)            ^ sw);
    aoff[1] = rb + ((g4 * 32 + 16)       ^ sw);
    aoff[2] = rb + ((128 + g4 * 32)      ^ sw);
    aoff[3] = rb + ((128 + g4 * 32 + 16) ^ sw);
#pragma unroll
    for (int nb = 0; nb < 4; ++nb)
        roff[nb] = rb + ((nb * 64 + g4 * 16) ^ sw);

    // ---- 3-deep pipeline: loads issued 2 compute-phases ahead ----
    stage(0, gw);
    stage(1, gw + NWAVES);

#pragma unroll
    for (int i = 0; i < TPW; ++i) {
        const int t = gw + i * NWAVES;
        if (i + 2 < TPW) {
            stage((i + 2) % 3, t + 2 * NWAVES);
            asm volatile("s_waitcnt vmcnt(8)" ::: "memory");   // tile i staged
        } else if (i + 2 == TPW) {
            asm volatile("s_waitcnt vmcnt(4)" ::: "memory");
        } else {
            asm volatile("s_waitcnt vmcnt(0)" ::: "memory");
        }
        __builtin_amdgcn_sched_barrier(0);

        const char* B = mybuf + (i % 3) * 4096;

        // B-operand fragments: S^T[k][n=lo16] = S[lo16][k], contiguous row
        f32x4 a0 = *(const f32x4*)(B + aoff[0]);
        f32x4 a1 = *(const f32x4*)(B + aoff[1]);
        f32x4 a2 = *(const f32x4*)(B + aoff[2]);
        f32x4 a3 = *(const f32x4*)(B + aoff[3]);

        // rv[nb] = S[lo16][16nb+4g4 .. +3] -> one b128 per nb
        f32x4 rv[4];
#pragma unroll
        for (int nb = 0; nb < 4; ++nb)
            rv[nb] = *(const f32x4*)(B + roff[nb]);

        union { bf16x8 v; unsigned u[4]; } af0, af1;
        af0.u[0] = pack2(a0[0], a0[1]);
        af0.u[1] = pack2(a0[2], a0[3]);
        af0.u[2] = pack2(a1[0], a1[1]);
        af0.u[3] = pack2(a1[2], a1[3]);
        af1.u[0] = pack2(a2[0], a2[1]);
        af1.u[1] = pack2(a2[2], a2[3]);
        af1.u[2] = pack2(a3[0], a3[1]);
        af1.u[3] = pack2(a3[2], a3[3]);

        // D = J*S^T + F : row m=16nb+4g4+q (spin), col n=lo16 (batch)
        f32x4 acc[4];
#pragma unroll
        for (int nb = 0; nb < 4; ++nb) acc[nb] = ffrag[nb];
#pragma unroll
        for (int nb = 0; nb < 4; ++nb) {
            acc[nb] = __builtin_amdgcn_mfma_f32_16x16x32_bf16(jf[nb][0], af0.v, acc[nb], 0, 0, 0);
            acc[nb] = __builtin_amdgcn_mfma_f32_16x16x32_bf16(jf[nb][1], af1.v, acc[nb], 0, 0, 0);
        }

        // H[b=lo16] = -sum_m s_b[m]*acc[m][b]; lane-local dot, 2-step reduce
        float p = 0.f;
#pragma unroll
        for (int nb = 0; nb < 4; ++nb) {
            p += rv[nb][0] * acc[nb][0];
            p += rv[nb][1] * acc[nb][1];
            p += rv[nb][2] * acc[nb][2];
            p += rv[nb][3] * acc[nb][3];
        }
        p += __shfl_xor(p, 16, 64);
        p += __shfl_xor(p, 32, 64);
        if (g4 == 0)
            out[t * 16 + lo16] = -p;   // lanes 0-15, coalesced 64B
    }
}

extern "C" void kernel_launch(void* const* d_in, const int* in_sizes, int n_in,
                              void* d_out, int out_size, void* d_ws, size_t ws_size,
                              hipStream_t stream) {
    const float* states    = (const float*)d_in[0];
    const float* couplings = (const float*)d_in[1];
    const float* fields    = (const float*)d_in[2];
    float* out = (float*)d_out;

    if (ws_size >= NSPIN * NSPIN * sizeof(__bf16)) {
        __bf16* Jg = (__bf16*)d_ws;
        build_J_kernel<<<16, 256, 0, stream>>>(couplings, Jg);
        ham_kernel<true><<<NBLOCKS, 256, 0, stream>>>(states, couplings, fields, Jg, out);
    } else {
        ham_kernel<false><<<NBLOCKS, 256, 0, stream>>>(states, couplings, fields, nullptr, out);
    }
}

// Round 10
// 47.304 us; speedup vs baseline: 1.5526x; 1.0901x over previous
//
#include <hip/hip_runtime.h>

#define NSPIN   64
#define BATCH_N 1000000
#define NTILES  (BATCH_N / 16)    // 62500 16-row tiles
#define NBLOCKS 3125
#define NWAVES  (NBLOCKS * 4)     // 12500 waves
#define TPW     (NTILES / NWAVES) // exactly 5 tiles/wave

typedef __bf16 bf16x8 __attribute__((ext_vector_type(8)));
typedef float  f32x4  __attribute__((ext_vector_type(4)));

// Build symmetric bf16 J (zero diag) from lower-tri coupling vector, once.
__global__ void build_J_kernel(const float* __restrict__ couplings,
                               __bf16* __restrict__ Jg) {
    int idx = blockIdx.x * blockDim.x + threadIdx.x;
    if (idx >= NSPIN * NSPIN) return;
    int r = idx >> 6, c = idx & 63;
    float v = 0.0f;
    if (r > c)      v = couplings[(r * (r - 1)) / 2 + c];
    else if (r < c) v = couplings[(c * (c - 1)) / 2 + r];
    Jg[idx] = (__bf16)v;
}

__device__ __forceinline__ unsigned fbits(float x) {
    union { float f; unsigned u; } cv; cv.f = x; return cv.u;
}
// pack two fp32 into packed bf16x2 (truncation — exact for +/-1.0)
__device__ __forceinline__ unsigned pack2(float lo, float hi) {
    return __builtin_amdgcn_perm(fbits(hi), fbits(lo), 0x07060302u);
}

// async global->LDS, 16B per lane; LDS dest = uniform base + lane*16
__device__ __forceinline__ void gload_lds16(const void* g, void* l) {
    __builtin_amdgcn_global_load_lds(
        (const __attribute__((address_space(1))) unsigned int*)g,
        (__attribute__((address_space(3))) unsigned int*)l, 16, 0, 0);
}

template<bool USE_WS>
__global__ __launch_bounds__(256, 4) void ham_kernel(
    const float* __restrict__ states,
    const float* __restrict__ couplings,
    const float* __restrict__ fields,
    const __bf16* __restrict__ Jg,
    float* __restrict__ out)
{
    // 4 waves x 3 x 4KB wave-private staging buffers (wave w at w*12K).
    // (!USE_WS: first 8KB temporarily holds J during the prologue.)
    __shared__ char smem[48 * 1024];

    const int lane = threadIdx.x & 63;
    const int wid  = threadIdx.x >> 6;
    const int lo16 = lane & 15;   // J row (A) / batch col (D)
    const int g4   = lane >> 4;   // k-group; D rows 4*g4+q
    const int gw   = blockIdx.x * 4 + wid;

    // A fragments (J rows): jf[nb][kb] = J[16nb+lo16][32kb+8g4+e]
    bf16x8 jf[4][2];
    if constexpr (USE_WS) {
#pragma unroll
        for (int nb = 0; nb < 4; ++nb)
#pragma unroll
            for (int kb = 0; kb < 2; ++kb)
                jf[nb][kb] = *(const bf16x8*)(Jg + (nb * 16 + lo16) * NSPIN + kb * 32 + g4 * 8);
    } else {
        __bf16* J = (__bf16*)smem;
        for (int i = threadIdx.x; i < NSPIN * NSPIN; i += 256) {
            int r = i >> 6, c = i & 63;
            float v = 0.0f;
            if (r > c)      v = couplings[(r * (r - 1)) / 2 + c];
            else if (r < c) v = couplings[(c * (c - 1)) / 2 + r];
            J[i] = (__bf16)v;
        }
        __syncthreads();
#pragma unroll
        for (int nb = 0; nb < 4; ++nb)
#pragma unroll
            for (int kb = 0; kb < 2; ++kb)
                jf[nb][kb] = *(const bf16x8*)(J + (nb * 16 + lo16) * NSPIN + kb * 32 + g4 * 8);
        __syncthreads();   // J region becomes wave0's staging buffers
    }

    // acc init = fields along m: ffrag[nb][q] = f[16nb+4g4+q]
    f32x4 ffrag[4];
#pragma unroll
    for (int nb = 0; nb < 4; ++nb)
        ffrag[nb] = *(const f32x4*)(fields + nb * 16 + g4 * 4);

    char* mybuf = smem + wid * (3 * 4096);   // three 4KB buffers, wave-private

    // Per-lane swizzled global source offsets for the 4 staging instrs.
    // LDS[row][chunk] = G[row][chunk ^ (row&7)]  (16B chunks, XOR involution)
    int srcoff[4];
#pragma unroll
    for (int j = 0; j < 4; ++j) {
        int row   = 4 * j + g4;
        int chunk = lo16 ^ (row & 7);
        srcoff[j] = row * 256 + chunk * 16;
    }

    const char* sbase = (const char*)states;
    auto stage = [&](int buf, int t) {
        const char* src = sbase + (size_t)t * 4096;
#pragma unroll
        for (int j = 0; j < 4; ++j)
            gload_lds16(src + srcoff[j], mybuf + buf * 4096 + j * 1024);
    };

    // Loop-invariant swizzled LDS read offsets (all reads use row = lo16):
    // addr(row, c) = row*256 + (c ^ ((row&7)<<4))
    const int sw  = (lo16 & 7) << 4;
    const int rb  = lo16 * 256;
    int aoff[4], roff[4];
    aoff[0] = rb + ((g4 * 32)            ^ sw);
    aoff[1] = rb + ((g4 * 32 + 16)       ^ sw);
    aoff[2] = rb + ((128 + g4 * 32)      ^ sw);
    aoff[3] = rb + ((128 + g4 * 32 + 16) ^ sw);
#pragma unroll
    for (int nb = 0; nb < 4; ++nb)
        roff[nb] = rb + ((nb * 64 + g4 * 16) ^ sw);

    // ---- 3-deep pipeline: loads issued 2 compute-phases ahead ----
    stage(0, gw);
    stage(1, gw + NWAVES);

#pragma unroll
    for (int i = 0; i < TPW; ++i) {
        const int t = gw + i * NWAVES;
        if (i + 2 < TPW) {
            stage((i + 2) % 3, t + 2 * NWAVES);
            asm volatile("s_waitcnt vmcnt(8)" ::: "memory");   // tile i staged
        } else if (i + 2 == TPW) {
            asm volatile("s_waitcnt vmcnt(4)" ::: "memory");
        } else {
            asm volatile("s_waitcnt vmcnt(0)" ::: "memory");
        }
        __builtin_amdgcn_sched_barrier(0);

        const char* B = mybuf + (i % 3) * 4096;

        // B-operand fragments: S^T[k][n=lo16] = S[lo16][k], contiguous row
        f32x4 a0 = *(const f32x4*)(B + aoff[0]);
        f32x4 a1 = *(const f32x4*)(B + aoff[1]);
        f32x4 a2 = *(const f32x4*)(B + aoff[2]);
        f32x4 a3 = *(const f32x4*)(B + aoff[3]);

        // rv[nb] = S[lo16][16nb+4g4 .. +3] -> one b128 per nb
        f32x4 rv[4];
#pragma unroll
        for (int nb = 0; nb < 4; ++nb)
            rv[nb] = *(const f32x4*)(B + roff[nb]);

        union { bf16x8 v; unsigned u[4]; } af0, af1;
        af0.u[0] = pack2(a0[0], a0[1]);
        af0.u[1] = pack2(a0[2], a0[3]);
        af0.u[2] = pack2(a1[0], a1[1]);
        af0.u[3] = pack2(a1[2], a1[3]);
        af1.u[0] = pack2(a2[0], a2[1]);
        af1.u[1] = pack2(a2[2], a2[3]);
        af1.u[2] = pack2(a3[0], a3[1]);
        af1.u[3] = pack2(a3[2], a3[3]);

        // D = J*S^T + F : row m=16nb+4g4+q (spin), col n=lo16 (batch)
        f32x4 acc[4];
#pragma unroll
        for (int nb = 0; nb < 4; ++nb) acc[nb] = ffrag[nb];
#pragma unroll
        for (int nb = 0; nb < 4; ++nb) {
            acc[nb] = __builtin_amdgcn_mfma_f32_16x16x32_bf16(jf[nb][0], af0.v, acc[nb], 0, 0, 0);
            acc[nb] = __builtin_amdgcn_mfma_f32_16x16x32_bf16(jf[nb][1], af1.v, acc[nb], 0, 0, 0);
        }

        // H[b=lo16] = -sum_m s_b[m]*acc[m][b]; lane-local dot, 2-step reduce
        float p = 0.f;
#pragma unroll
        for (int nb = 0; nb < 4; ++nb) {
            p += rv[nb][0] * acc[nb][0];
            p += rv[nb][1] * acc[nb][1];
            p += rv[nb][2] * acc[nb][2];
            p += rv[nb][3] * acc[nb][3];
        }
        p += __shfl_xor(p, 16, 64);
        p += __shfl_xor(p, 32, 64);
        if (g4 == 0)
            out[t * 16 + lo16] = -p;   // lanes 0-15, coalesced 64B
    }
}

extern "C" void kernel_launch(void* const* d_in, const int* in_sizes, int n_in,
                              void* d_out, int out_size, void* d_ws, size_t ws_size,
                              hipStream_t stream) {
    const float* states    = (const float*)d_in[0];
    const float* couplings = (const float*)d_in[1];
    const float* fields    = (const float*)d_in[2];
    float* out = (float*)d_out;

    if (ws_size >= NSPIN * NSPIN * sizeof(__bf16)) {
        __bf16* Jg = (__bf16*)d_ws;
        build_J_kernel<<<16, 256, 0, stream>>>(couplings, Jg);
        ham_kernel<true><<<NBLOCKS, 256, 0, stream>>>(states, couplings, fields, Jg, out);
    } else {
        ham_kernel<false><<<NBLOCKS, 256, 0, stream>>>(states, couplings, fields, nullptr, out);
    }
}